// Round 7
// baseline (2894.587 us; speedup 1.0000x reference)
//
#include <hip/hip_runtime.h>

#define N_NODES 50000
#define N_EDGES 800000
#define D 128

// ---------------- graph build ----------------

__global__ void deg_kernel(const int* __restrict__ dst, int* __restrict__ deg) {
  int e = blockIdx.x * 256 + threadIdx.x;
  if (e < N_EDGES) atomicAdd(&deg[dst[e]], 1);
}

// single-block scan (1024 thr = 16 waves), wave-shuffle based:
// exclusive prefix over deg -> row_start (+ cursor copy), plus inv = 1/(deg+1)
__global__ void scan_kernel(const int* __restrict__ deg, int* __restrict__ row_start,
                            int* __restrict__ cursor, float* __restrict__ inv) {
  __shared__ int wsum[16];
  __shared__ int carry_s;
  const int t = threadIdx.x;
  const int lane = t & 63, wid = t >> 6;
  if (t == 0) carry_s = 0;
  __syncthreads();
  for (int base = 0; base < N_NODES; base += 4096) {
    int i0 = base + t * 4;
    int v[4];
    int s = 0;
#pragma unroll
    for (int j = 0; j < 4; ++j) {
      int i = i0 + j;
      v[j] = (i < N_NODES) ? deg[i] : 0;
      s += v[j];
    }
    // wave-inclusive scan of s
    int run = s;
#pragma unroll
    for (int off = 1; off < 64; off <<= 1) {
      int o = __shfl_up(run, off);
      if (lane >= off) run += o;
    }
    if (lane == 63) wsum[wid] = run;
    __syncthreads();
    if (t < 16) {
      int w = wsum[t];
#pragma unroll
      for (int off = 1; off < 16; off <<= 1) {
        int o = __shfl_up(w, off, 16);
        if (t >= off) w += o;
      }
      wsum[t] = w;  // inclusive over wave sums
    }
    __syncthreads();
    int excl = carry_s + (wid ? wsum[wid - 1] : 0) + run - s;
#pragma unroll
    for (int j = 0; j < 4; ++j) {
      int i = i0 + j;
      if (i < N_NODES) {
        row_start[i] = excl;
        cursor[i] = excl;
        inv[i] = 1.0f / (float)(v[j] + 1);
      }
      excl += v[j];
    }
    __syncthreads();
    if (t == 0) carry_s += wsum[15];
    __syncthreads();
  }
  if (t == 0) row_start[N_NODES] = carry_s;
}

__global__ void csr_kernel(const int* __restrict__ src, const int* __restrict__ dst,
                           int* __restrict__ cursor, int* __restrict__ csr) {
  int e = blockIdx.x * 256 + threadIdx.x;
  if (e < N_EDGES) {
    int p = atomicAdd(&cursor[dst[e]], 1);  // cursor pre-seeded with row_start
    csr[p] = src[e];
  }
}

// transpose the three weight matrices into ws: wT[k][o] = W[o][k]
__global__ void wtrans_kernel(const float* __restrict__ W1, const float* __restrict__ W2,
                              const float* __restrict__ W3, float* __restrict__ wT) {
  int g = blockIdx.x * 256 + threadIdx.x;
  if (g < 16384) {
    int k = g >> 7, o = g & 127;
    wT[g] = W1[o * 128 + k];
  } else if (g < 32768) {
    int l = g - 16384;
    int k = l >> 7, o = l & 127;
    wT[g] = W2[o * 128 + k];
  } else if (g < 40960) {
    int l = g - 32768;
    int k = l >> 6, o = l & 63;
    wT[g] = W3[o * 128 + k];
  }
}

// ---------------- per-layer kernels ----------------

// CSR gather over DV-dim rows: out[n] = relu?( (G[n] + sum_nbr G[nbr]) * inv[n] )
// BW-bound at ~3.7 TB/s (measured r4/r5: ILP 4->8 and occupancy 68->58% both
// leave time at 58.5us); FETCH ~186MB = 8 XCDs x compulsory table fill.
template <int DV, bool RELU>
__global__ __launch_bounds__(256) void agg_kernel(const float* __restrict__ G,
    const int* __restrict__ row_start, const int* __restrict__ csr,
    const float* __restrict__ inv, float* __restrict__ outA) {
  constexpr int L = DV / 4;    // lanes per row
  constexpr int NPW = 64 / L;  // nodes per wave
  const int wave = (blockIdx.x * 256 + threadIdx.x) >> 6;
  const int lane = threadIdx.x & 63;
  const int sub = lane / L;
  const int li = lane % L;
  const int node = wave * NPW + sub;

  const float4* hp = (const float4*)G;
  float4 acc = hp[(size_t)node * L + li];
  float4 acc2 = make_float4(0.f, 0.f, 0.f, 0.f);
  const int s = row_start[node], e = row_start[node + 1];
  int j = s;
  for (; j + 8 <= e; j += 8) {
    int n0 = csr[j + 0], n1 = csr[j + 1], n2 = csr[j + 2], n3 = csr[j + 3];
    int n4 = csr[j + 4], n5 = csr[j + 5], n6 = csr[j + 6], n7 = csr[j + 7];
    float4 v0 = hp[(size_t)n0 * L + li];
    float4 v1 = hp[(size_t)n1 * L + li];
    float4 v2 = hp[(size_t)n2 * L + li];
    float4 v3 = hp[(size_t)n3 * L + li];
    float4 v4 = hp[(size_t)n4 * L + li];
    float4 v5 = hp[(size_t)n5 * L + li];
    float4 v6 = hp[(size_t)n6 * L + li];
    float4 v7 = hp[(size_t)n7 * L + li];
    acc.x  += (v0.x + v1.x) + (v2.x + v3.x);
    acc.y  += (v0.y + v1.y) + (v2.y + v3.y);
    acc.z  += (v0.z + v1.z) + (v2.z + v3.z);
    acc.w  += (v0.w + v1.w) + (v2.w + v3.w);
    acc2.x += (v4.x + v5.x) + (v6.x + v7.x);
    acc2.y += (v4.y + v5.y) + (v6.y + v7.y);
    acc2.z += (v4.z + v5.z) + (v6.z + v7.z);
    acc2.w += (v4.w + v5.w) + (v6.w + v7.w);
  }
  for (; j + 4 <= e; j += 4) {
    int n0 = csr[j + 0], n1 = csr[j + 1], n2 = csr[j + 2], n3 = csr[j + 3];
    float4 v0 = hp[(size_t)n0 * L + li];
    float4 v1 = hp[(size_t)n1 * L + li];
    float4 v2 = hp[(size_t)n2 * L + li];
    float4 v3 = hp[(size_t)n3 * L + li];
    acc.x += (v0.x + v1.x) + (v2.x + v3.x);
    acc.y += (v0.y + v1.y) + (v2.y + v3.y);
    acc.z += (v0.z + v1.z) + (v2.z + v3.z);
    acc.w += (v0.w + v1.w) + (v2.w + v3.w);
  }
  for (; j < e; ++j) {
    int nb = csr[j];
    float4 v = hp[(size_t)nb * L + li];
    acc2.x += v.x; acc2.y += v.y; acc2.z += v.z; acc2.w += v.w;
  }
  acc.x += acc2.x; acc.y += acc2.y; acc.z += acc2.z; acc.w += acc2.w;
  float iv = inv[node];
  acc.x *= iv; acc.y *= iv; acc.z *= iv; acc.w *= iv;
  if (RELU) {
    acc.x = fmaxf(acc.x, 0.f); acc.y = fmaxf(acc.y, 0.f);
    acc.z = fmaxf(acc.z, 0.f); acc.w = fmaxf(acc.w, 0.f);
  }
  ((float4*)outA)[(size_t)node * L + li] = acc;
}

// f32 GEMM: out[r][o] = A[r][:] . wT[:][o], A: [N][128], wT: [128][DOUT]
// Block: 128 rows x DOUT outs, 256 threads, thread tile 8 x TO (TO=DOUT/16),
// K staged in 2 tiles of 64. Per kb: 8 A-b128 + TO W-b128 vs 64*TO/2 FMA-instr
// -> VALU-bound ~2.7:1. Wave = 8 rowT x 8 outT so A-reads hit 8 distinct bank
// groups (kb^rowT swizzle) and W-reads are <=2-way (free).
template <int DOUT>
__global__ __launch_bounds__(256, 2) void gemm_kernel(const float* __restrict__ A,
    const float* __restrict__ wT, float* __restrict__ out) {
  constexpr int TO = DOUT / 16;  // outs per thread (8 or 4)
  __shared__ float aL[128 * 64];   // [row][k4 ^ (row>>3) : 4]  (32 KB)
  __shared__ float wL[64 * DOUT];  // [k][o]                    (32/16 KB)
  const int t = threadIdx.x;
  const int row0 = blockIdx.x * 128;

  // lane mapping: wave = 8 rowT x 8 outT
  const int w = t >> 6, l = t & 63;
  const int rowT = (l >> 3) + ((w >> 1) << 3);  // 0..15
  const int outT = (l & 7) + ((w & 1) << 3);    // 0..15

  const float4* A4 = (const float4*)A;
  const float4* w4 = (const float4*)wT;
  float4* aL4 = (float4*)aL;
  float4* wL4 = (float4*)wL;
  const float4* aL4c = (const float4*)aL;
  const float4* wL4c = (const float4*)wL;

  float acc[8][TO];
#pragma unroll
  for (int i = 0; i < 8; ++i)
#pragma unroll
    for (int j = 0; j < TO; ++j) acc[i][j] = 0.f;

#pragma unroll
  for (int kt = 0; kt < 2; ++kt) {
    if (kt) __syncthreads();
    // stage A: 128 rows x 16 float4 (cols kt*64..+63)
#pragma unroll
    for (int i = 0; i < 8; ++i) {
      int g4 = t + i * 256;      // 0..2047
      int r = g4 >> 4;           // 0..127
      int k4 = g4 & 15;
      int gr = row0 + r;
      float4 v = make_float4(0.f, 0.f, 0.f, 0.f);
      if (gr < N_NODES) v = A4[(size_t)gr * 32 + kt * 16 + k4];
      aL4[r * 16 + (k4 ^ ((r >> 3) & 15))] = v;
    }
    // stage W: 64 k x DOUT/4 float4
#pragma unroll
    for (int i = 0; i < TO; ++i) {
      int g4 = t + i * 256;            // 0..64*DOUT/4-1
      int k = g4 / (DOUT / 4);
      int o4 = g4 % (DOUT / 4);
      wL4[k * (DOUT / 4) + o4] = w4[(size_t)(kt * 64 + k) * (DOUT / 4) + o4];
    }
    __syncthreads();

#pragma unroll
    for (int kb = 0; kb < 16; ++kb) {
      float4 a[8];
#pragma unroll
      for (int i = 0; i < 8; ++i)
        a[i] = aL4c[(rowT * 8 + i) * 16 + (kb ^ rowT)];
#pragma unroll
      for (int dk = 0; dk < 4; ++dk) {
#pragma unroll
        for (int j4 = 0; j4 < TO / 4; ++j4) {
          float4 b = wL4c[(kb * 4 + dk) * (DOUT / 4) + outT * (TO / 4) + j4];
#pragma unroll
          for (int i = 0; i < 8; ++i) {
            float av = ((const float*)&a[i])[dk];
            acc[i][j4 * 4 + 0] += av * b.x;
            acc[i][j4 * 4 + 1] += av * b.y;
            acc[i][j4 * 4 + 2] += av * b.z;
            acc[i][j4 * 4 + 3] += av * b.w;
          }
        }
      }
    }
  }

#pragma unroll
  for (int i = 0; i < 8; ++i) {
    int gr = row0 + rowT * 8 + i;
    if (gr < N_NODES) {
#pragma unroll
      for (int j4 = 0; j4 < TO / 4; ++j4) {
        float4 v = make_float4(acc[i][j4 * 4 + 0], acc[i][j4 * 4 + 1],
                               acc[i][j4 * 4 + 2], acc[i][j4 * 4 + 3]);
        *(float4*)&out[(size_t)gr * DOUT + outT * TO + j4 * 4] = v;
      }
    }
  }
}

// ---------------- launch ----------------

extern "C" void kernel_launch(void* const* d_in, const int* in_sizes, int n_in,
                              void* d_out, int out_size, void* d_ws, size_t ws_size,
                              hipStream_t stream) {
  const float* x  = (const float*)d_in[0];
  const int* ei   = (const int*)d_in[1];
  const float* W1 = (const float*)d_in[2];
  const float* W2 = (const float*)d_in[3];
  const float* W3 = (const float*)d_in[4];
  const int* src = ei;
  const int* dst = ei + N_EDGES;
  float* out = (float*)d_out;

  // workspace layout (256B-aligned chunks)
  char* ws = (char*)d_ws;
  size_t off = 0;
  auto alloc = [&](size_t bytes) {
    void* p = ws + off;
    off += (bytes + 255) & ~(size_t)255;
    return p;
  };
  int* deg       = (int*)alloc(N_NODES * sizeof(int));
  int* row_start = (int*)alloc((N_NODES + 1) * sizeof(int));
  int* cursor    = (int*)alloc(N_NODES * sizeof(int));
  int* csr       = (int*)alloc(N_EDGES * sizeof(int));
  float* inv     = (float*)alloc(N_NODES * sizeof(float));
  float* wT      = (float*)alloc((16384 + 16384 + 8192) * sizeof(float));
  float* G       = (float*)alloc((size_t)N_NODES * D * sizeof(float));
  float* H       = (float*)alloc((size_t)N_NODES * D * sizeof(float));
  (void)ws_size;

  float* wT1 = wT;
  float* wT2 = wT + 16384;
  float* wT3 = wT + 32768;

  hipMemsetAsync(deg, 0, N_NODES * sizeof(int), stream);

  const int eblocks = (N_EDGES + 255) / 256;
  deg_kernel<<<eblocks, 256, 0, stream>>>(dst, deg);
  scan_kernel<<<1, 1024, 0, stream>>>(deg, row_start, cursor, inv);
  csr_kernel<<<eblocks, 256, 0, stream>>>(src, dst, cursor, csr);
  wtrans_kernel<<<(40960 + 255) / 256, 256, 0, stream>>>(W1, W2, W3, wT);

  const int gblocks = (N_NODES + 127) / 128;  // 391

  // layer l: G = h @ Wl^T, then h' = relu(agg(G))   [agg and GEMM commute]
  // layer 1: x -> G -> H
  gemm_kernel<128><<<gblocks, 256, 0, stream>>>(x, wT1, G);
  agg_kernel<128, true><<<6250, 256, 0, stream>>>(G, row_start, csr, inv, H);
  // layer 2: H -> G -> H
  gemm_kernel<128><<<gblocks, 256, 0, stream>>>(H, wT2, G);
  agg_kernel<128, true><<<6250, 256, 0, stream>>>(G, row_start, csr, inv, H);
  // layer 3: H -> G(64) -> out (final relu fused into agg)
  gemm_kernel<64><<<gblocks, 256, 0, stream>>>(H, wT3, G);
  agg_kernel<64, true><<<3125, 256, 0, stream>>>(G, row_start, csr, inv, out);
}

// Round 8
// 439.637 us; speedup vs baseline: 6.5840x; 6.5840x over previous
//
#include <hip/hip_runtime.h>

#define N_NODES 50000
#define N_EDGES 800000
#define D 128

// ---------------- graph build ----------------

__global__ void deg_kernel(const int* __restrict__ dst, int* __restrict__ deg) {
  int e = blockIdx.x * 256 + threadIdx.x;
  if (e < N_EDGES) atomicAdd(&deg[dst[e]], 1);
}

// single-block scan (1024 thr = 16 waves), wave-shuffle based:
// exclusive prefix over deg -> row_start (+ cursor copy), plus inv = 1/(deg+1)
__global__ void scan_kernel(const int* __restrict__ deg, int* __restrict__ row_start,
                            int* __restrict__ cursor, float* __restrict__ inv) {
  __shared__ int wsum[16];
  __shared__ int carry_s;
  const int t = threadIdx.x;
  const int lane = t & 63, wid = t >> 6;
  if (t == 0) carry_s = 0;
  __syncthreads();
  for (int base = 0; base < N_NODES; base += 4096) {
    int i0 = base + t * 4;
    int v[4];
    int s = 0;
#pragma unroll
    for (int j = 0; j < 4; ++j) {
      int i = i0 + j;
      v[j] = (i < N_NODES) ? deg[i] : 0;
      s += v[j];
    }
    // wave-inclusive scan of s
    int run = s;
#pragma unroll
    for (int off = 1; off < 64; off <<= 1) {
      int o = __shfl_up(run, off);
      if (lane >= off) run += o;
    }
    if (lane == 63) wsum[wid] = run;
    __syncthreads();
    if (t < 16) {
      int w = wsum[t];
#pragma unroll
      for (int off = 1; off < 16; off <<= 1) {
        int o = __shfl_up(w, off, 16);
        if (t >= off) w += o;
      }
      wsum[t] = w;  // inclusive over wave sums
    }
    __syncthreads();
    int excl = carry_s + (wid ? wsum[wid - 1] : 0) + run - s;
#pragma unroll
    for (int j = 0; j < 4; ++j) {
      int i = i0 + j;
      if (i < N_NODES) {
        row_start[i] = excl;
        cursor[i] = excl;
        inv[i] = 1.0f / (float)(v[j] + 1);
      }
      excl += v[j];
    }
    __syncthreads();
    if (t == 0) carry_s += wsum[15];
    __syncthreads();
  }
  if (t == 0) row_start[N_NODES] = carry_s;
}

__global__ void csr_kernel(const int* __restrict__ src, const int* __restrict__ dst,
                           int* __restrict__ cursor, int* __restrict__ csr) {
  int e = blockIdx.x * 256 + threadIdx.x;
  if (e < N_EDGES) {
    int p = atomicAdd(&cursor[dst[e]], 1);  // cursor pre-seeded with row_start
    csr[p] = src[e];
  }
}

// transpose the three weight matrices into ws: wT[k][o] = W[o][k]
__global__ void wtrans_kernel(const float* __restrict__ W1, const float* __restrict__ W2,
                              const float* __restrict__ W3, float* __restrict__ wT) {
  int g = blockIdx.x * 256 + threadIdx.x;
  if (g < 16384) {
    int k = g >> 7, o = g & 127;
    wT[g] = W1[o * 128 + k];
  } else if (g < 32768) {
    int l = g - 16384;
    int k = l >> 7, o = l & 127;
    wT[g] = W2[o * 128 + k];
  } else if (g < 40960) {
    int l = g - 32768;
    int k = l >> 6, o = l & 63;
    wT[g] = W3[o * 128 + k];
  }
}

// ---------------- per-layer kernels ----------------

// CSR gather over DV-dim rows: out[n] = relu?( (G[n] + sum_nbr G[nbr]) * inv[n] )
// BW-bound at ~3.7 TB/s (measured r4/r5: ILP 4->8 and occupancy 68->58% both
// leave time at 58.5us); FETCH ~186MB = 8 XCDs x compulsory table fill.
template <int DV, bool RELU>
__global__ __launch_bounds__(256) void agg_kernel(const float* __restrict__ G,
    const int* __restrict__ row_start, const int* __restrict__ csr,
    const float* __restrict__ inv, float* __restrict__ outA) {
  constexpr int L = DV / 4;    // lanes per row
  constexpr int NPW = 64 / L;  // nodes per wave
  const int wave = (blockIdx.x * 256 + threadIdx.x) >> 6;
  const int lane = threadIdx.x & 63;
  const int sub = lane / L;
  const int li = lane % L;
  const int node = wave * NPW + sub;

  const float4* hp = (const float4*)G;
  float4 acc = hp[(size_t)node * L + li];
  float4 acc2 = make_float4(0.f, 0.f, 0.f, 0.f);
  const int s = row_start[node], e = row_start[node + 1];
  int j = s;
  for (; j + 8 <= e; j += 8) {
    int n0 = csr[j + 0], n1 = csr[j + 1], n2 = csr[j + 2], n3 = csr[j + 3];
    int n4 = csr[j + 4], n5 = csr[j + 5], n6 = csr[j + 6], n7 = csr[j + 7];
    float4 v0 = hp[(size_t)n0 * L + li];
    float4 v1 = hp[(size_t)n1 * L + li];
    float4 v2 = hp[(size_t)n2 * L + li];
    float4 v3 = hp[(size_t)n3 * L + li];
    float4 v4 = hp[(size_t)n4 * L + li];
    float4 v5 = hp[(size_t)n5 * L + li];
    float4 v6 = hp[(size_t)n6 * L + li];
    float4 v7 = hp[(size_t)n7 * L + li];
    acc.x  += (v0.x + v1.x) + (v2.x + v3.x);
    acc.y  += (v0.y + v1.y) + (v2.y + v3.y);
    acc.z  += (v0.z + v1.z) + (v2.z + v3.z);
    acc.w  += (v0.w + v1.w) + (v2.w + v3.w);
    acc2.x += (v4.x + v5.x) + (v6.x + v7.x);
    acc2.y += (v4.y + v5.y) + (v6.y + v7.y);
    acc2.z += (v4.z + v5.z) + (v6.z + v7.z);
    acc2.w += (v4.w + v5.w) + (v6.w + v7.w);
  }
  for (; j + 4 <= e; j += 4) {
    int n0 = csr[j + 0], n1 = csr[j + 1], n2 = csr[j + 2], n3 = csr[j + 3];
    float4 v0 = hp[(size_t)n0 * L + li];
    float4 v1 = hp[(size_t)n1 * L + li];
    float4 v2 = hp[(size_t)n2 * L + li];
    float4 v3 = hp[(size_t)n3 * L + li];
    acc.x += (v0.x + v1.x) + (v2.x + v3.x);
    acc.y += (v0.y + v1.y) + (v2.y + v3.y);
    acc.z += (v0.z + v1.z) + (v2.z + v3.z);
    acc.w += (v0.w + v1.w) + (v2.w + v3.w);
  }
  for (; j < e; ++j) {
    int nb = csr[j];
    float4 v = hp[(size_t)nb * L + li];
    acc2.x += v.x; acc2.y += v.y; acc2.z += v.z; acc2.w += v.w;
  }
  acc.x += acc2.x; acc.y += acc2.y; acc.z += acc2.z; acc.w += acc2.w;
  float iv = inv[node];
  acc.x *= iv; acc.y *= iv; acc.z *= iv; acc.w *= iv;
  if (RELU) {
    acc.x = fmaxf(acc.x, 0.f); acc.y = fmaxf(acc.y, 0.f);
    acc.z = fmaxf(acc.z, 0.f); acc.w = fmaxf(acc.w, 0.f);
  }
  ((float4*)outA)[(size_t)node * L + li] = acc;
}

// f32 GEMM: out[r][o] = A[r][:] . wT[:][o], A: [N][128], wT: [128][DOUT]
// Block: 128 rows x DOUT outs, 256 threads, thread tile 8 x TO (TO=DOUT/16),
// K staged in 2 tiles of 64. Per kb: 8 A-b128 + TO W-b128 vs 64*TO/2 FMA-instr
// -> VALU-bound ~2.7:1. Wave = 8 rowT x 8 outT; A-reads 2-way via kb^rowT
// swizzle, W-reads 2-way (both free per m136).
// r7 lesson (rule #20): NEVER extract fragment scalars via
// ((float*)&a[i])[dk] — address-taking defeated SROA, spilled a[]+acc to
// scratch (FETCH 1.6GB, 1060us). Named components (.x/.y/.z/.w) only.
template <int DOUT>
__global__ __launch_bounds__(256, 2) void gemm_kernel(const float* __restrict__ A,
    const float* __restrict__ wT, float* __restrict__ out) {
  constexpr int TO = DOUT / 16;  // outs per thread (8 or 4)
  __shared__ float aL[128 * 64];   // [row][k4 ^ (row>>3) : 4]  (32 KB)
  __shared__ float wL[64 * DOUT];  // [k][o]                    (32/16 KB)
  const int t = threadIdx.x;
  const int row0 = blockIdx.x * 128;

  // lane mapping: wave = 8 rowT x 8 outT
  const int w = t >> 6, l = t & 63;
  const int rowT = (l >> 3) + ((w >> 1) << 3);  // 0..15
  const int outT = (l & 7) + ((w & 1) << 3);    // 0..15

  const float4* A4 = (const float4*)A;
  const float4* w4 = (const float4*)wT;
  float4* aL4 = (float4*)aL;
  float4* wL4 = (float4*)wL;
  const float4* aL4c = (const float4*)aL;
  const float4* wL4c = (const float4*)wL;

  float acc[8][TO];
#pragma unroll
  for (int i = 0; i < 8; ++i)
#pragma unroll
    for (int j = 0; j < TO; ++j) acc[i][j] = 0.f;

// one dk-step: extract a[i].COMP (named component — no address-taking)
#define DK_STEP(COMP, DK)                                                  \
  {                                                                        \
    _Pragma("unroll")                                                      \
    for (int j4 = 0; j4 < TO / 4; ++j4) {                                  \
      float4 b = wL4c[(kb * 4 + (DK)) * (DOUT / 4) + outT * (TO / 4) + j4];\
      _Pragma("unroll")                                                    \
      for (int i = 0; i < 8; ++i) {                                        \
        float av = a[i].COMP;                                              \
        acc[i][j4 * 4 + 0] += av * b.x;                                    \
        acc[i][j4 * 4 + 1] += av * b.y;                                    \
        acc[i][j4 * 4 + 2] += av * b.z;                                    \
        acc[i][j4 * 4 + 3] += av * b.w;                                    \
      }                                                                    \
    }                                                                      \
  }

#pragma unroll
  for (int kt = 0; kt < 2; ++kt) {
    if (kt) __syncthreads();
    // stage A: 128 rows x 16 float4 (cols kt*64..+63)
#pragma unroll
    for (int i = 0; i < 8; ++i) {
      int g4 = t + i * 256;      // 0..2047
      int r = g4 >> 4;           // 0..127
      int k4 = g4 & 15;
      int gr = row0 + r;
      float4 v = make_float4(0.f, 0.f, 0.f, 0.f);
      if (gr < N_NODES) v = A4[(size_t)gr * 32 + kt * 16 + k4];
      aL4[r * 16 + (k4 ^ ((r >> 3) & 15))] = v;
    }
    // stage W: 64 k x DOUT/4 float4
#pragma unroll
    for (int i = 0; i < TO; ++i) {
      int g4 = t + i * 256;            // 0..64*DOUT/4-1
      int k = g4 / (DOUT / 4);
      int o4 = g4 % (DOUT / 4);
      wL4[k * (DOUT / 4) + o4] = w4[(size_t)(kt * 64 + k) * (DOUT / 4) + o4];
    }
    __syncthreads();

    for (int kb = 0; kb < 16; ++kb) {
      float4 a[8];
#pragma unroll
      for (int i = 0; i < 8; ++i)
        a[i] = aL4c[(rowT * 8 + i) * 16 + (kb ^ rowT)];
      DK_STEP(x, 0)
      DK_STEP(y, 1)
      DK_STEP(z, 2)
      DK_STEP(w, 3)
    }
  }
#undef DK_STEP

#pragma unroll
  for (int i = 0; i < 8; ++i) {
    int gr = row0 + rowT * 8 + i;
    if (gr < N_NODES) {
#pragma unroll
      for (int j4 = 0; j4 < TO / 4; ++j4) {
        float4 v = make_float4(acc[i][j4 * 4 + 0], acc[i][j4 * 4 + 1],
                               acc[i][j4 * 4 + 2], acc[i][j4 * 4 + 3]);
        *(float4*)&out[(size_t)gr * DOUT + outT * TO + j4 * 4] = v;
      }
    }
  }
}

// ---------------- launch ----------------

extern "C" void kernel_launch(void* const* d_in, const int* in_sizes, int n_in,
                              void* d_out, int out_size, void* d_ws, size_t ws_size,
                              hipStream_t stream) {
  const float* x  = (const float*)d_in[0];
  const int* ei   = (const int*)d_in[1];
  const float* W1 = (const float*)d_in[2];
  const float* W2 = (const float*)d_in[3];
  const float* W3 = (const float*)d_in[4];
  const int* src = ei;
  const int* dst = ei + N_EDGES;
  float* out = (float*)d_out;

  // workspace layout (256B-aligned chunks)
  char* ws = (char*)d_ws;
  size_t off = 0;
  auto alloc = [&](size_t bytes) {
    void* p = ws + off;
    off += (bytes + 255) & ~(size_t)255;
    return p;
  };
  int* deg       = (int*)alloc(N_NODES * sizeof(int));
  int* row_start = (int*)alloc((N_NODES + 1) * sizeof(int));
  int* cursor    = (int*)alloc(N_NODES * sizeof(int));
  int* csr       = (int*)alloc(N_EDGES * sizeof(int));
  float* inv     = (float*)alloc(N_NODES * sizeof(float));
  float* wT      = (float*)alloc((16384 + 16384 + 8192) * sizeof(float));
  float* G       = (float*)alloc((size_t)N_NODES * D * sizeof(float));
  float* H       = (float*)alloc((size_t)N_NODES * D * sizeof(float));
  (void)ws_size;

  float* wT1 = wT;
  float* wT2 = wT + 16384;
  float* wT3 = wT + 32768;

  hipMemsetAsync(deg, 0, N_NODES * sizeof(int), stream);

  const int eblocks = (N_EDGES + 255) / 256;
  deg_kernel<<<eblocks, 256, 0, stream>>>(dst, deg);
  scan_kernel<<<1, 1024, 0, stream>>>(deg, row_start, cursor, inv);
  csr_kernel<<<eblocks, 256, 0, stream>>>(src, dst, cursor, csr);
  wtrans_kernel<<<(40960 + 255) / 256, 256, 0, stream>>>(W1, W2, W3, wT);

  const int gblocks = (N_NODES + 127) / 128;  // 391

  // layer l: G = h @ Wl^T, then h' = relu(agg(G))   [agg and GEMM commute]
  // layer 1: x -> G -> H
  gemm_kernel<128><<<gblocks, 256, 0, stream>>>(x, wT1, G);
  agg_kernel<128, true><<<6250, 256, 0, stream>>>(G, row_start, csr, inv, H);
  // layer 2: H -> G -> H
  gemm_kernel<128><<<gblocks, 256, 0, stream>>>(H, wT2, G);
  agg_kernel<128, true><<<6250, 256, 0, stream>>>(G, row_start, csr, inv, H);
  // layer 3: H -> G(64) -> out (final relu fused into agg)
  gemm_kernel<64><<<gblocks, 256, 0, stream>>>(H, wT3, G);
  agg_kernel<64, true><<<3125, 256, 0, stream>>>(G, row_start, csr, inv, out);
}